// Round 13
// baseline (276.855 us; speedup 1.0000x reference)
//
#include <hip/hip_runtime.h>
#include <hip/hip_bf16.h>
#include <hip/hip_fp16.h>

#define HIDDEN 768
#define NTOK   4096
#define SEQ    1024
#define NBATCH 4
#define NHEADS 12
#define KAUG   (HIDDEN * 9)   // 6912
#define NQKV   (3 * HIDDEN)   // 2304

using bf16 = __hip_bfloat16;
using fp16 = __half;
typedef __attribute__((ext_vector_type(4))) float f32x4;
typedef __attribute__((ext_vector_type(8))) short bf16x8;
typedef __attribute__((ext_vector_type(8))) _Float16 h16x8;

__device__ inline void gload_lds16(const void* g, void* l) {
    __builtin_amdgcn_global_load_lds((const __attribute__((address_space(1))) void*)g,
                                     (__attribute__((address_space(3))) void*)l, 16, 0, 0);
}

// ==== prep: X_aug + W_aug in ONE launch ====
__global__ __launch_bounds__(256) void prep(const float* __restrict__ x,
        const float* __restrict__ qbw, const float* __restrict__ qsw, const float* __restrict__ qsc,
        const float* __restrict__ kbw, const float* __restrict__ ksw, const float* __restrict__ ksc,
        const float* __restrict__ vbw, const float* __restrict__ vsw, const float* __restrict__ vsc,
        bf16* __restrict__ xa, bf16* __restrict__ wa) {
    int blk = blockIdx.x;
    const int tid = threadIdx.x;
    if (blk < 12288) {                       // --- X_aug ---
        int gid = blk * 256 + tid;
        float xv = x[gid];
        int n = gid / HIDDEN;
        int i = gid - n * HIDDEN;
        float sil = xv / (1.0f + __expf(-xv));
        float g[12];
#pragma unroll
        for (int k = 0; k < 12; ++k) g[k] = (float)(k - 3) * 0.4f - 1.0f;
        float b[11];
#pragma unroll
        for (int c = 0; c < 11; ++c) b[c] = (xv >= g[c] && xv < g[c + 1]) ? 1.0f : 0.0f;
#pragma unroll
        for (int k = 1; k <= 3; ++k) {
#pragma unroll
            for (int c = 0; c < 11; ++c) {
                if (c < 11 - k) {
                    float left  = (xv - g[c]) / (g[c + k] - g[c]) * b[c];
                    float right = (g[c + k + 1] - xv) / (g[c + k + 1] - g[c + 1]) * b[c + 1];
                    b[c] = left + right;
                }
            }
        }
        bf16* dst = xa + (size_t)n * KAUG + (size_t)i * 9;
        dst[0] = __float2bfloat16(sil);
#pragma unroll
        for (int c = 0; c < 8; ++c) dst[1 + c] = __float2bfloat16(b[c]);
        return;
    }
    blk -= 12288;                            // --- W_aug q/k/v ---
    int job = blk / 2304;
    int gid = (blk - job * 2304) * 256 + tid;
    const float* bw = job == 0 ? qbw : (job == 1 ? kbw : vbw);
    const float* sw = job == 0 ? qsw : (job == 1 ? ksw : vsw);
    const float* sc = job == 0 ? qsc : (job == 1 ? ksc : vsc);
    float bwv = bw[gid];
    float scv = sc[gid];
    bf16* dst = wa + (size_t)job * HIDDEN * KAUG + (size_t)gid * 9;
    dst[0] = __float2bfloat16(bwv);
#pragma unroll
    for (int c = 0; c < 8; ++c)
        dst[1 + c] = __float2bfloat16(sw[(size_t)gid * 8 + c] * scv);
}

// ==== 8-phase 256x256 GEMM: C_slab[z] = A@B^T (K-slice z), fp16 plain stores ====
template <int KSPLIT>
__global__ __launch_bounds__(512, 2) void gemm256_8ph(const bf16* __restrict__ A,
                                                      const bf16* __restrict__ B,
                                                      fp16* __restrict__ C,
                                                      int M, int N, int K) {
    extern __shared__ char smem[];   // 128 KiB: [buf(2)][half(4)] x 16KB
    const int tid  = threadIdx.x;
    const int lane = tid & 63;
    const int wave = tid >> 6;
    const int wm = wave >> 2;
    const int wn = wave & 3;

    // T1: bijective XCD swizzle within the x-y plane (nwg=144, 144%8==0)
    const int nwg = gridDim.x * gridDim.y;
    const int per = nwg >> 3;
    int lin = blockIdx.y * gridDim.x + blockIdx.x;
    int swz = (lin & 7) * per + (lin >> 3);
    const int row0 = (swz % gridDim.x) * 256;
    const int col0 = (swz / gridDim.x) * 256;

    const int kslice = K / KSPLIT;
    const int koff = blockIdx.z * kslice;
    const int ntiles = kslice >> 6;
    fp16* Cs = C + (size_t)blockIdx.z * M * N;

    const int lr = lane & 15;
    const int lk = (lane >> 4) * 8;
    const int xorv = (lr & 7) << 4;

    f32x4 acc[8][4];
#pragma unroll
    for (int m = 0; m < 8; ++m)
#pragma unroll
        for (int n = 0; n < 4; ++n) acc[m][n] = f32x4{0.f, 0.f, 0.f, 0.f};

    auto stage_half = [&](int buf, int half, int t) {
#pragma unroll
        for (int j = 0; j < 2; ++j) {
            int idx = tid + j * 512;
            int r = idx >> 3;
            int swzc = ((((idx & 7) * 16) ^ ((r & 7) << 4)) >> 1);
            const bf16* src = (half < 2)
                ? A + (size_t)(row0 + half * 128 + r) * K + koff + t * 64 + swzc
                : B + (size_t)(col0 + (half - 2) * 128 + r) * K + koff + t * 64 + swzc;
            gload_lds16(src, smem + ((size_t)(buf * 4 + half) << 14) + idx * 16);
        }
    };
    auto rdA = [&](int buf, int mh, bf16x8 (&af)[4][2]) {
        const char* Ab = smem + ((size_t)(buf * 4 + wm) << 14);
#pragma unroll
        for (int m = 0; m < 4; ++m)
#pragma unroll
            for (int kk = 0; kk < 2; ++kk)
                af[m][kk] = *(const bf16x8*)(Ab + (mh * 64 + m * 16 + lr) * 128 +
                                             (((kk * 32 + lk) * 2) ^ xorv));
    };
    auto rdB = [&](int buf, int nh, bf16x8 (&bf)[2][2]) {
        const char* Bb = smem + ((size_t)(buf * 4 + 2 + (wn >> 1)) << 14);
#pragma unroll
        for (int n = 0; n < 2; ++n)
#pragma unroll
            for (int kk = 0; kk < 2; ++kk)
                bf[n][kk] = *(const bf16x8*)(Bb + ((wn & 1) * 64 + nh * 32 + n * 16 + lr) * 128 +
                                             (((kk * 32 + lk) * 2) ^ xorv));
    };

    stage_half(0, 0, 0); stage_half(0, 1, 0); stage_half(0, 2, 0); stage_half(0, 3, 0);
    stage_half(1, 2, 1); stage_half(1, 3, 1);
    asm volatile("s_waitcnt vmcnt(0)" ::: "memory");
    __builtin_amdgcn_s_barrier();

    bf16x8 af[4][2], bf0[2][2], bf1[2][2];

#define QUAD(MH, NH, BF)                                                         \
    __builtin_amdgcn_s_setprio(1);                                               \
    _Pragma("unroll") for (int m = 0; m < 4; ++m)                                \
        _Pragma("unroll") for (int n = 0; n < 2; ++n)                            \
            _Pragma("unroll") for (int kk = 0; kk < 2; ++kk)                     \
                acc[(MH)*4 + m][(NH)*2 + n] = __builtin_amdgcn_mfma_f32_16x16x32_bf16( \
                    af[m][kk], BF[n][kk], acc[(MH)*4 + m][(NH)*2 + n], 0, 0, 0); \
    __builtin_amdgcn_s_setprio(0);

    for (int u = 0; u < ntiles; ++u) {
        const int buf = u & 1, nbuf = buf ^ 1;
        rdA(buf, 0, af);
        rdB(buf, 0, bf0);
        if (u + 1 < ntiles) stage_half(nbuf, 0, u + 1);
        __builtin_amdgcn_s_barrier();
        asm volatile("s_waitcnt lgkmcnt(0)" ::: "memory");
        __builtin_amdgcn_sched_barrier(0);
        QUAD(0, 0, bf0)
        __builtin_amdgcn_sched_barrier(0);
        __builtin_amdgcn_s_barrier();
        rdB(buf, 1, bf1);
        if (u + 1 < ntiles) stage_half(nbuf, 1, u + 1);
        __builtin_amdgcn_s_barrier();
        asm volatile("s_waitcnt lgkmcnt(0)" ::: "memory");
        __builtin_amdgcn_sched_barrier(0);
        QUAD(0, 1, bf1)
        __builtin_amdgcn_sched_barrier(0);
        __builtin_amdgcn_s_barrier();
        rdA(buf, 1, af);
        if (u + 2 < ntiles) stage_half(buf, 2, u + 2);
        __builtin_amdgcn_s_barrier();
        asm volatile("s_waitcnt lgkmcnt(0)" ::: "memory");
        __builtin_amdgcn_sched_barrier(0);
        QUAD(1, 1, bf1)
        __builtin_amdgcn_sched_barrier(0);
        __builtin_amdgcn_s_barrier();
        if (u + 2 < ntiles) {
            stage_half(buf, 3, u + 2);
            asm volatile("s_waitcnt vmcnt(4)" ::: "memory");
        } else {
            asm volatile("s_waitcnt vmcnt(0)" ::: "memory");
        }
        __builtin_amdgcn_s_barrier();
        __builtin_amdgcn_sched_barrier(0);
        QUAD(1, 0, bf0)
        __builtin_amdgcn_sched_barrier(0);
        __builtin_amdgcn_s_barrier();
    }
#undef QUAD

    const int cr = (lane >> 4) * 4;
    const int cc = lane & 15;
#pragma unroll
    for (int am = 0; am < 8; ++am) {
#pragma unroll
        for (int an = 0; an < 4; ++an) {
            int c = col0 + wn * 64 + an * 16 + cc;
#pragma unroll
            for (int j = 0; j < 4; ++j) {
                int r = row0 + wm * 128 + am * 16 + cr + j;
                Cs[(size_t)r * N + c] = __float2half(acc[am][an][j]);
            }
        }
    }
}

// ---- 128x128 GEMM (out-proj): swizzled LDS, 2-phase dbuf, T1 XCD swizzle ----
__global__ __launch_bounds__(256) void gemm_bt(const bf16* __restrict__ A,
                                               const bf16* __restrict__ B,
                                               float* __restrict__ C,
                                               const float* __restrict__ bias,
                                               int M, int N, int K) {
    __shared__ __align__(16) bf16 As[2][128][64];
    __shared__ __align__(16) bf16 Bs[2][128][64];
    const int tid  = threadIdx.x;
    const int lane = tid & 63;
    const int wave = tid >> 6;
    const int wr = wave >> 1, wc = wave & 1;

    // T1 bijective XCD swizzle (nwg = 32*6 = 192, 192%8==0)
    const int gx = gridDim.x;
    const int per = (gx * gridDim.y) >> 3;
    int lin = blockIdx.y * gx + blockIdx.x;
    int swz = (lin & 7) * per + (lin >> 3);
    const int row0 = (swz % gx) * 128;
    const int col0 = (swz / gx) * 128;

    f32x4 acc[4][4];
#pragma unroll
    for (int m = 0; m < 4; ++m)
#pragma unroll
        for (int n = 0; n < 4; ++n) acc[m][n] = f32x4{0.f, 0.f, 0.f, 0.f};

    const int srow = tid >> 3;
    const int scol = ((((tid & 7) * 16) ^ ((srow & 7) << 4)) >> 1);
    const bf16* aptr = A + (size_t)(row0 + srow) * K + scol;
    const bf16* bptr = B + (size_t)(col0 + srow) * K + scol;

    const int lr = lane & 15;
    const int lk = (lane >> 4) * 8;
    const int xorv = (lr & 7) << 4;
    const int nt = K >> 6;

    auto stage = [&](int buf, int k0) {
        char* adst = (char*)&As[buf][0][0] + tid * 16;
        char* bdst = (char*)&Bs[buf][0][0] + tid * 16;
#pragma unroll
        for (int j = 0; j < 4; ++j)
            gload_lds16(aptr + (size_t)j * 32 * K + k0, adst + j * 4096);
#pragma unroll
        for (int j = 0; j < 4; ++j)
            gload_lds16(bptr + (size_t)j * 32 * K + k0, bdst + j * 4096);
    };

    stage(0, 0);
    asm volatile("s_waitcnt vmcnt(0)" ::: "memory");
    __syncthreads();

    int cur = 0;
    for (int t = 0; t < nt; ++t) {
        if (t + 1 < nt) stage(cur ^ 1, (t + 1) << 6);
        __builtin_amdgcn_s_setprio(1);
#pragma unroll
        for (int kk = 0; kk < 64; kk += 32) {
            const int cb = ((kk + lk) * 2) ^ xorv;
            bf16x8 af[4], bfv[4];
#pragma unroll
            for (int m = 0; m < 4; ++m)
                af[m] = *(const bf16x8*)((char*)&As[cur][0][0] + (wr * 64 + m * 16 + lr) * 128 + cb);
#pragma unroll
            for (int n = 0; n < 4; ++n)
                bfv[n] = *(const bf16x8*)((char*)&Bs[cur][0][0] + (wc * 64 + n * 16 + lr) * 128 + cb);
#pragma unroll
            for (int m = 0; m < 4; ++m)
#pragma unroll
                for (int n = 0; n < 4; ++n)
                    acc[m][n] = __builtin_amdgcn_mfma_f32_16x16x32_bf16(af[m], bfv[n], acc[m][n], 0, 0, 0);
        }
        __builtin_amdgcn_s_setprio(0);
        __builtin_amdgcn_sched_barrier(0);
        if (t + 1 < nt)
            asm volatile("s_waitcnt vmcnt(0)" ::: "memory");
        __builtin_amdgcn_s_barrier();
        __builtin_amdgcn_sched_barrier(0);
        cur ^= 1;
    }

    const int cr = (lane >> 4) * 4;
    const int cc = lane & 15;
#pragma unroll
    for (int m = 0; m < 4; ++m) {
#pragma unroll
        for (int n = 0; n < 4; ++n) {
            int c = col0 + wc * 64 + n * 16 + cc;
            float bv = bias ? bias[c] : 0.0f;
#pragma unroll
            for (int j = 0; j < 4; ++j) {
                int r = row0 + wr * 64 + m * 16 + cr + j;
                C[(size_t)r * N + c] = acc[m][n][j] + bv;
            }
        }
    }
}

// ==== rope_vt: {q/k rope}, {V 3-slab sum + LDS transpose}, {out_w cvt} ====
__global__ __launch_bounds__(256) void rope_vt(const fp16* __restrict__ qkv0,
                                               bf16* __restrict__ qb,
                                               bf16* __restrict__ kb,
                                               bf16* __restrict__ vbT,
                                               const float* __restrict__ ow,
                                               bf16* __restrict__ owb) {
    __shared__ bf16 tile[64][65];
    const fp16* qkv1 = qkv0 + (size_t)NTOK * NQKV;
    const fp16* qkv2 = qkv1 + (size_t)NTOK * NQKV;
    int blk = blockIdx.x;
    const int tid = threadIdx.x;
    if (blk < 6144) {                        // --- q/k rope ---
        int gid = blk * 256 + tid;
        int d = gid & 31;
        int h = (gid >> 5) % NHEADS;
        int n = gid / (32 * NHEADS);
        int s = n & (SEQ - 1);
        int b = n >> 10;
        float inv = __expf(-(float)d * 0.28782313662425574f);  // 10000^(-d/32)
        float th = (float)s * inv;
        float sn, cs;
        sincosf(th, &sn, &cs);
        size_t src = (size_t)n * NQKV + h * 64 + d;
        auto rd = [&](size_t idx) {
            return __half2float(qkv0[idx]) + __half2float(qkv1[idx]) + __half2float(qkv2[idx]);
        };
        float q0 = rd(src),       q1 = rd(src + 32);
        float k0 = rd(src + 768), k1 = rd(src + 800);
        int bh = b * NHEADS + h;
        size_t dst = ((size_t)bh * SEQ + s) * 64 + d;
        const float QS = 0.18033688011f;     // 0.125 * log2(e)
        qb[dst]      = __float2bfloat16((q0 * cs - q1 * sn) * QS);
        qb[dst + 32] = __float2bfloat16((q1 * cs + q0 * sn) * QS);
        kb[dst]      = __float2bfloat16(k0 * cs - k1 * sn);
        kb[dst + 32] = __float2bfloat16(k1 * cs + k0 * sn);
        return;
    }
    blk -= 6144;
    if (blk < 768) {                         // --- V transpose ---
        int bh = blk >> 4, st = blk & 15;
        int b = bh / NHEADS, h = bh - b * NHEADS;
        {
            int s = tid >> 2, d0 = (tid & 3) * 16;
            size_t src = (size_t)(b * SEQ + st * 64 + s) * NQKV + 1536 + h * 64 + d0;
#pragma unroll
            for (int c = 0; c < 2; ++c) {
                h16x8 a0 = *(const h16x8*)(qkv0 + src + c * 8);
                h16x8 a1 = *(const h16x8*)(qkv1 + src + c * 8);
                h16x8 a2 = *(const h16x8*)(qkv2 + src + c * 8);
#pragma unroll
                for (int j = 0; j < 8; ++j)
                    tile[s][d0 + c * 8 + j] =
                        __float2bfloat16((float)a0[j] + (float)a1[j] + (float)a2[j]);
            }
        }
        __syncthreads();
        {
            int d = tid >> 2, s0 = (tid & 3) * 16;
            bf16 out[16];
#pragma unroll
            for (int i = 0; i < 16; ++i) out[i] = tile[s0 + i][d];
            bf16* dst = vbT + ((size_t)bh * 64 + d) * SEQ + st * 64 + s0;
            *(bf16x8*)(dst)     = *(bf16x8*)&out[0];
            *(bf16x8*)(dst + 8) = *(bf16x8*)&out[8];
        }
        return;
    }
    blk -= 768;                              // --- out_w cvt (post-GEMM1 alias) ---
    int gid = blk * 256 + tid;
    owb[gid] = __float2bfloat16(ow[gid]);
}

// ---- MFMA flash attention: 512-thr block, 8 waves share one K/V staging ----
// q-tile = 128 rows (wave w owns rows w*16..w*16+15); 24 waves/CU occupancy.
__global__ __launch_bounds__(512) void attn_mfma(const bf16* __restrict__ qb,
                                                 const bf16* __restrict__ kb,
                                                 const bf16* __restrict__ vbT,
                                                 bf16* __restrict__ attnb) {
    __shared__ __align__(16) bf16 Kls[2][64][64];
    __shared__ __align__(16) bf16 Vt[2][64][64];
    __shared__ __align__(16) bf16 Pls[8][16][72];

    const int tid  = threadIdx.x;
    const int lane = tid & 63;
    const int w    = tid >> 6;               // 0..7
    const int bh   = blockIdx.x;
    const int b    = bh / NHEADS, h = bh - b * NHEADS;
    const int qt   = blockIdx.y;             // 0..7 (128-row q-tiles)

    const bf16* qhead  = qb  + (size_t)bh * SEQ * 64;
    const char* khead  = (const char*)(kb  + (size_t)bh * SEQ * 64);
    const char* vheadT = (const char*)(vbT + (size_t)bh * 64 * SEQ);

    const int lr = lane & 15;
    const int lg = lane >> 4;
    const int xorv = (lr & 7) << 4;

    bf16x8 qf[2];
    {
        const bf16* qrow = qhead + (size_t)(qt * 128 + w * 16 + lr) * 64 + lg * 8;
        qf[0] = *(const bf16x8*)qrow;
        qf[1] = *(const bf16x8*)(qrow + 32);
    }

    f32x4 oacc[4];
#pragma unroll
    for (int n = 0; n < 4; ++n) oacc[n] = f32x4{0.f, 0.f, 0.f, 0.f};
    float mrun[4], lsum[4];
#pragma unroll
    for (int j = 0; j < 4; ++j) { mrun[j] = -3.0e38f; lsum[j] = 0.0f; }

    auto stage = [&](int bufi, int t) {      // 512 threads: 1 K-load + 1 V-load each
        int r = tid >> 3;
        int swz = ((tid & 7) * 16) ^ ((r & 7) << 4);
        gload_lds16(khead + (size_t)(t * 64 + r) * 128 + swz,
                    (char*)&Kls[bufi][0][0] + tid * 16);
        gload_lds16(vheadT + (size_t)r * (SEQ * 2) + t * 128 + swz,
                    (char*)&Vt[bufi][0][0] + tid * 16);
    };

    stage(0, 0);
    asm volatile("s_waitcnt vmcnt(0)" ::: "memory");
    __builtin_amdgcn_s_barrier();

    for (int t = 0; t < SEQ / 64; ++t) {
        const int bufi = t & 1;
        if (t + 1 < SEQ / 64) stage(bufi ^ 1, t + 1);

        f32x4 sacc[4];   // scores in log2 domain (Q pre-scaled)
#pragma unroll
        for (int n = 0; n < 4; ++n) sacc[n] = f32x4{0.f, 0.f, 0.f, 0.f};
        __builtin_amdgcn_s_setprio(1);
#pragma unroll
        for (int c = 0; c < 2; ++c)
#pragma unroll
            for (int n = 0; n < 4; ++n) {
                bf16x8 kf = *(const bf16x8*)((char*)&Kls[bufi][0][0] +
                                             (n * 16 + lr) * 128 + (((c * 32 + lg * 8) * 2) ^ xorv));
                sacc[n] = __builtin_amdgcn_mfma_f32_16x16x32_bf16(qf[c], kf, sacc[n], 0, 0, 0);
            }
        __builtin_amdgcn_s_setprio(0);

        // T13 defer-max in log2 units (11.5 ≈ 8 nats)
        float rowmax[4];
        bool viol = false;
#pragma unroll
        for (int j = 0; j < 4; ++j) {
            rowmax[j] = fmaxf(fmaxf(sacc[0][j], sacc[1][j]), fmaxf(sacc[2][j], sacc[3][j]));
            viol |= rowmax[j] > mrun[j] + 11.5f;
        }
        if (__ballot(viol) != 0ull) {
#pragma unroll
            for (int j = 0; j < 4; ++j) {
                float mx = rowmax[j];
                mx = fmaxf(mx, __shfl_xor(mx, 1));
                mx = fmaxf(mx, __shfl_xor(mx, 2));
                mx = fmaxf(mx, __shfl_xor(mx, 4));
                mx = fmaxf(mx, __shfl_xor(mx, 8));
                float mnew = fmaxf(mrun[j], mx);
                float csc = exp2f(mrun[j] - mnew);
                mrun[j] = mnew;
                lsum[j] *= csc;
#pragma unroll
                for (int n = 0; n < 4; ++n) oacc[n][j] *= csc;
            }
        }

        float pj[4][4];
#pragma unroll
        for (int j = 0; j < 4; ++j) {
            float p0 = exp2f(sacc[0][j] - mrun[j]);
            float p1 = exp2f(sacc[1][j] - mrun[j]);
            float p2 = exp2f(sacc[2][j] - mrun[j]);
            float p3 = exp2f(sacc[3][j] - mrun[j]);
            pj[0][j] = p0; pj[1][j] = p1; pj[2][j] = p2; pj[3][j] = p3;
            lsum[j] += (p0 + p1) + (p2 + p3);
        }

#pragma unroll
        for (int n = 0; n < 4; ++n)
#pragma unroll
            for (int j = 0; j < 4; ++j)
                Pls[w][lg * 4 + j][n * 16 + lr] = __float2bfloat16(pj[n][j]);

        __builtin_amdgcn_s_setprio(1);
#pragma unroll
        for (int c = 0; c < 2; ++c) {
            bf16x8 pf = *(const bf16x8*)&Pls[w][lr][c * 32 + lg * 8];
#pragma unroll
            for (int n = 0; n < 4; ++n) {
                bf16x8 vf = *(const bf16x8*)((char*)&Vt[bufi][0][0] +
                                             (n * 16 + lr) * 128 + (((c * 32 + lg * 8) * 2) ^ xorv));
                oacc[n] = __builtin_amdgcn_mfma_f32_16x16x32_bf16(pf, vf, oacc[n], 0, 0, 0);
            }
        }
        __builtin_amdgcn_s_setprio(0);

        if (t + 1 < SEQ / 64)
            asm volatile("s_waitcnt vmcnt(0)" ::: "memory");
        __builtin_amdgcn_s_barrier();
    }

#pragma unroll
    for (int j = 0; j < 4; ++j) {
        float l = lsum[j];
        l += __shfl_xor(l, 1);
        l += __shfl_xor(l, 2);
        l += __shfl_xor(l, 4);
        l += __shfl_xor(l, 8);
        float invl = 1.0f / l;
        int tok = b * SEQ + qt * 128 + w * 16 + lg * 4 + j;
        bf16* dst = attnb + (size_t)tok * HIDDEN + h * 64;
#pragma unroll
        for (int n = 0; n < 4; ++n)
            dst[n * 16 + lr] = __float2bfloat16(oacc[n][j] * invl);
    }
}

extern "C" void kernel_launch(void* const* d_in, const int* in_sizes, int n_in,
                              void* d_out, int out_size, void* d_ws, size_t ws_size,
                              hipStream_t stream) {
    const float* x   = (const float*)d_in[0];
    const float* qbw = (const float*)d_in[1];
    const float* qsw = (const float*)d_in[2];
    const float* qsc = (const float*)d_in[3];
    const float* kbw = (const float*)d_in[4];
    const float* ksw = (const float*)d_in[5];
    const float* ksc = (const float*)d_in[6];
    const float* vbw = (const float*)d_in[7];
    const float* vsw = (const float*)d_in[8];
    const float* vsc = (const float*)d_in[9];
    const float* ow  = (const float*)d_in[10];
    const float* ob  = (const float*)d_in[11];

    char* ws = (char*)d_ws;
    size_t off = 0;
    bf16*  xaug = (bf16*)(ws + off); off += (size_t)NTOK * KAUG * 2;        // 56.6 MB
    bf16*  waug = (bf16*)(ws + off); off += (size_t)NQKV * KAUG * 2;        // 31.9 MB
    fp16*  qkvp = (fp16*)(ws + off); off += (size_t)3 * NTOK * NQKV * 2;    // 56.6 MB (3 slabs)
    if (off > ws_size) return;

    bf16* attnb = xaug;                                    // xaug dead after GEMM1
    bf16* owb   = (bf16*)((char*)xaug + (8u << 20));       // ditto (written in rope_vt)
    const size_t headsz = (size_t)NTOK * 64 * NHEADS;
    bf16* qb  = waug;                                      // waug dead after GEMM1
    bf16* kb  = waug + headsz;
    bf16* vbT = waug + 2 * headsz;

    hipFuncSetAttribute(reinterpret_cast<const void*>(gemm256_8ph<3>),
                        hipFuncAttributeMaxDynamicSharedMemorySize, 131072);

    prep<<<12288 + 3 * 2304, 256, 0, stream>>>(
        x, qbw, qsw, qsc, kbw, ksw, ksc, vbw, vsw, vsc, xaug, waug);

    gemm256_8ph<3><<<dim3(NTOK / 256, NQKV / 256, 3), 512, 131072, stream>>>(
        xaug, waug, qkvp, NTOK, NQKV, KAUG);

    rope_vt<<<6144 + 768 + 2304, 256, 0, stream>>>(qkvp, qb, kb, vbT, ow, owb);
    attn_mfma<<<dim3(NBATCH * NHEADS, SEQ / 128), 512, 0, stream>>>(qb, kb, vbT, attnb);
    gemm_bt<<<dim3(NTOK / 128, HIDDEN / 128), 256, 0, stream>>>(attnb, owb, (float*)d_out, ob, NTOK, HIDDEN, HIDDEN);
}

// Round 14
// 271.347 us; speedup vs baseline: 1.0203x; 1.0203x over previous
//
#include <hip/hip_runtime.h>
#include <hip/hip_bf16.h>
#include <hip/hip_fp16.h>

#define HIDDEN 768
#define NTOK   4096
#define SEQ    1024
#define NBATCH 4
#define NHEADS 12
#define KAUG   (HIDDEN * 9)   // 6912
#define NQKV   (3 * HIDDEN)   // 2304

using bf16 = __hip_bfloat16;
using fp16 = __half;
typedef __attribute__((ext_vector_type(4))) float f32x4;
typedef __attribute__((ext_vector_type(8))) short bf16x8;
typedef __attribute__((ext_vector_type(8))) _Float16 h16x8;

__device__ inline void gload_lds16(const void* g, void* l) {
    __builtin_amdgcn_global_load_lds((const __attribute__((address_space(1))) void*)g,
                                     (__attribute__((address_space(3))) void*)l, 16, 0, 0);
}

// ==== prep: X_aug + W_aug in ONE launch ====
__global__ __launch_bounds__(256) void prep(const float* __restrict__ x,
        const float* __restrict__ qbw, const float* __restrict__ qsw, const float* __restrict__ qsc,
        const float* __restrict__ kbw, const float* __restrict__ ksw, const float* __restrict__ ksc,
        const float* __restrict__ vbw, const float* __restrict__ vsw, const float* __restrict__ vsc,
        bf16* __restrict__ xa, bf16* __restrict__ wa) {
    int blk = blockIdx.x;
    const int tid = threadIdx.x;
    if (blk < 12288) {                       // --- X_aug ---
        int gid = blk * 256 + tid;
        float xv = x[gid];
        int n = gid / HIDDEN;
        int i = gid - n * HIDDEN;
        float sil = xv / (1.0f + __expf(-xv));
        float g[12];
#pragma unroll
        for (int k = 0; k < 12; ++k) g[k] = (float)(k - 3) * 0.4f - 1.0f;
        float b[11];
#pragma unroll
        for (int c = 0; c < 11; ++c) b[c] = (xv >= g[c] && xv < g[c + 1]) ? 1.0f : 0.0f;
#pragma unroll
        for (int k = 1; k <= 3; ++k) {
#pragma unroll
            for (int c = 0; c < 11; ++c) {
                if (c < 11 - k) {
                    float left  = (xv - g[c]) / (g[c + k] - g[c]) * b[c];
                    float right = (g[c + k + 1] - xv) / (g[c + k + 1] - g[c + 1]) * b[c + 1];
                    b[c] = left + right;
                }
            }
        }
        bf16* dst = xa + (size_t)n * KAUG + (size_t)i * 9;
        dst[0] = __float2bfloat16(sil);
#pragma unroll
        for (int c = 0; c < 8; ++c) dst[1 + c] = __float2bfloat16(b[c]);
        return;
    }
    blk -= 12288;                            // --- W_aug q/k/v ---
    int job = blk / 2304;
    int gid = (blk - job * 2304) * 256 + tid;
    const float* bw = job == 0 ? qbw : (job == 1 ? kbw : vbw);
    const float* sw = job == 0 ? qsw : (job == 1 ? ksw : vsw);
    const float* sc = job == 0 ? qsc : (job == 1 ? ksc : vsc);
    float bwv = bw[gid];
    float scv = sc[gid];
    bf16* dst = wa + (size_t)job * HIDDEN * KAUG + (size_t)gid * 9;
    dst[0] = __float2bfloat16(bwv);
#pragma unroll
    for (int c = 0; c < 8; ++c)
        dst[1 + c] = __float2bfloat16(sw[(size_t)gid * 8 + c] * scv);
}

// ==== 8-phase 256x256 GEMM: C_slab[z] = A@B^T (K-slice z), fp16 plain stores ====
template <int KSPLIT>
__global__ __launch_bounds__(512, 2) void gemm256_8ph(const bf16* __restrict__ A,
                                                      const bf16* __restrict__ B,
                                                      fp16* __restrict__ C,
                                                      int M, int N, int K) {
    extern __shared__ char smem[];   // 128 KiB: [buf(2)][half(4)] x 16KB
    const int tid  = threadIdx.x;
    const int lane = tid & 63;
    const int wave = tid >> 6;
    const int wm = wave >> 2;
    const int wn = wave & 3;

    // T1: bijective XCD swizzle within the x-y plane (nwg=144, 144%8==0)
    const int nwg = gridDim.x * gridDim.y;
    const int per = nwg >> 3;
    int lin = blockIdx.y * gridDim.x + blockIdx.x;
    int swz = (lin & 7) * per + (lin >> 3);
    const int row0 = (swz % gridDim.x) * 256;
    const int col0 = (swz / gridDim.x) * 256;

    const int kslice = K / KSPLIT;
    const int koff = blockIdx.z * kslice;
    const int ntiles = kslice >> 6;
    fp16* Cs = C + (size_t)blockIdx.z * M * N;

    const int lr = lane & 15;
    const int lk = (lane >> 4) * 8;
    const int xorv = (lr & 7) << 4;

    f32x4 acc[8][4];
#pragma unroll
    for (int m = 0; m < 8; ++m)
#pragma unroll
        for (int n = 0; n < 4; ++n) acc[m][n] = f32x4{0.f, 0.f, 0.f, 0.f};

    auto stage_half = [&](int buf, int half, int t) {
#pragma unroll
        for (int j = 0; j < 2; ++j) {
            int idx = tid + j * 512;
            int r = idx >> 3;
            int swzc = ((((idx & 7) * 16) ^ ((r & 7) << 4)) >> 1);
            const bf16* src = (half < 2)
                ? A + (size_t)(row0 + half * 128 + r) * K + koff + t * 64 + swzc
                : B + (size_t)(col0 + (half - 2) * 128 + r) * K + koff + t * 64 + swzc;
            gload_lds16(src, smem + ((size_t)(buf * 4 + half) << 14) + idx * 16);
        }
    };
    auto rdA = [&](int buf, int mh, bf16x8 (&af)[4][2]) {
        const char* Ab = smem + ((size_t)(buf * 4 + wm) << 14);
#pragma unroll
        for (int m = 0; m < 4; ++m)
#pragma unroll
            for (int kk = 0; kk < 2; ++kk)
                af[m][kk] = *(const bf16x8*)(Ab + (mh * 64 + m * 16 + lr) * 128 +
                                             (((kk * 32 + lk) * 2) ^ xorv));
    };
    auto rdB = [&](int buf, int nh, bf16x8 (&bf)[2][2]) {
        const char* Bb = smem + ((size_t)(buf * 4 + 2 + (wn >> 1)) << 14);
#pragma unroll
        for (int n = 0; n < 2; ++n)
#pragma unroll
            for (int kk = 0; kk < 2; ++kk)
                bf[n][kk] = *(const bf16x8*)(Bb + ((wn & 1) * 64 + nh * 32 + n * 16 + lr) * 128 +
                                             (((kk * 32 + lk) * 2) ^ xorv));
    };

    stage_half(0, 0, 0); stage_half(0, 1, 0); stage_half(0, 2, 0); stage_half(0, 3, 0);
    stage_half(1, 2, 1); stage_half(1, 3, 1);
    asm volatile("s_waitcnt vmcnt(0)" ::: "memory");
    __builtin_amdgcn_s_barrier();

    bf16x8 af[4][2], bf0[2][2], bf1[2][2];

#define QUAD(MH, NH, BF)                                                         \
    __builtin_amdgcn_s_setprio(1);                                               \
    _Pragma("unroll") for (int m = 0; m < 4; ++m)                                \
        _Pragma("unroll") for (int n = 0; n < 2; ++n)                            \
            _Pragma("unroll") for (int kk = 0; kk < 2; ++kk)                     \
                acc[(MH)*4 + m][(NH)*2 + n] = __builtin_amdgcn_mfma_f32_16x16x32_bf16( \
                    af[m][kk], BF[n][kk], acc[(MH)*4 + m][(NH)*2 + n], 0, 0, 0); \
    __builtin_amdgcn_s_setprio(0);

    for (int u = 0; u < ntiles; ++u) {
        const int buf = u & 1, nbuf = buf ^ 1;
        rdA(buf, 0, af);
        rdB(buf, 0, bf0);
        if (u + 1 < ntiles) stage_half(nbuf, 0, u + 1);
        __builtin_amdgcn_s_barrier();
        asm volatile("s_waitcnt lgkmcnt(0)" ::: "memory");
        __builtin_amdgcn_sched_barrier(0);
        QUAD(0, 0, bf0)
        __builtin_amdgcn_sched_barrier(0);
        __builtin_amdgcn_s_barrier();
        rdB(buf, 1, bf1);
        if (u + 1 < ntiles) stage_half(nbuf, 1, u + 1);
        __builtin_amdgcn_s_barrier();
        asm volatile("s_waitcnt lgkmcnt(0)" ::: "memory");
        __builtin_amdgcn_sched_barrier(0);
        QUAD(0, 1, bf1)
        __builtin_amdgcn_sched_barrier(0);
        __builtin_amdgcn_s_barrier();
        rdA(buf, 1, af);
        if (u + 2 < ntiles) stage_half(buf, 2, u + 2);
        __builtin_amdgcn_s_barrier();
        asm volatile("s_waitcnt lgkmcnt(0)" ::: "memory");
        __builtin_amdgcn_sched_barrier(0);
        QUAD(1, 1, bf1)
        __builtin_amdgcn_sched_barrier(0);
        __builtin_amdgcn_s_barrier();
        if (u + 2 < ntiles) {
            stage_half(buf, 3, u + 2);
            asm volatile("s_waitcnt vmcnt(4)" ::: "memory");
        } else {
            asm volatile("s_waitcnt vmcnt(0)" ::: "memory");
        }
        __builtin_amdgcn_s_barrier();
        __builtin_amdgcn_sched_barrier(0);
        QUAD(1, 0, bf0)
        __builtin_amdgcn_sched_barrier(0);
        __builtin_amdgcn_s_barrier();
    }
#undef QUAD

    const int cr = (lane >> 4) * 4;
    const int cc = lane & 15;
#pragma unroll
    for (int am = 0; am < 8; ++am) {
#pragma unroll
        for (int an = 0; an < 4; ++an) {
            int c = col0 + wn * 64 + an * 16 + cc;
#pragma unroll
            for (int j = 0; j < 4; ++j) {
                int r = row0 + wm * 128 + am * 16 + cr + j;
                Cs[(size_t)r * N + c] = __float2half(acc[am][an][j]);
            }
        }
    }
}

// ---- 128x128 GEMM (out-proj): swizzled LDS, 2-phase dbuf, T1 XCD swizzle ----
__global__ __launch_bounds__(256) void gemm_bt(const bf16* __restrict__ A,
                                               const bf16* __restrict__ B,
                                               float* __restrict__ C,
                                               const float* __restrict__ bias,
                                               int M, int N, int K) {
    __shared__ __align__(16) bf16 As[2][128][64];
    __shared__ __align__(16) bf16 Bs[2][128][64];
    const int tid  = threadIdx.x;
    const int lane = tid & 63;
    const int wave = tid >> 6;
    const int wr = wave >> 1, wc = wave & 1;

    // T1 bijective XCD swizzle (nwg = 32*6 = 192, 192%8==0)
    const int gx = gridDim.x;
    const int per = (gx * gridDim.y) >> 3;
    int lin = blockIdx.y * gx + blockIdx.x;
    int swz = (lin & 7) * per + (lin >> 3);
    const int row0 = (swz % gx) * 128;
    const int col0 = (swz / gx) * 128;

    f32x4 acc[4][4];
#pragma unroll
    for (int m = 0; m < 4; ++m)
#pragma unroll
        for (int n = 0; n < 4; ++n) acc[m][n] = f32x4{0.f, 0.f, 0.f, 0.f};

    const int srow = tid >> 3;
    const int scol = ((((tid & 7) * 16) ^ ((srow & 7) << 4)) >> 1);
    const bf16* aptr = A + (size_t)(row0 + srow) * K + scol;
    const bf16* bptr = B + (size_t)(col0 + srow) * K + scol;

    const int lr = lane & 15;
    const int lk = (lane >> 4) * 8;
    const int xorv = (lr & 7) << 4;
    const int nt = K >> 6;

    auto stage = [&](int buf, int k0) {
        char* adst = (char*)&As[buf][0][0] + tid * 16;
        char* bdst = (char*)&Bs[buf][0][0] + tid * 16;
#pragma unroll
        for (int j = 0; j < 4; ++j)
            gload_lds16(aptr + (size_t)j * 32 * K + k0, adst + j * 4096);
#pragma unroll
        for (int j = 0; j < 4; ++j)
            gload_lds16(bptr + (size_t)j * 32 * K + k0, bdst + j * 4096);
    };

    stage(0, 0);
    asm volatile("s_waitcnt vmcnt(0)" ::: "memory");
    __syncthreads();

    int cur = 0;
    for (int t = 0; t < nt; ++t) {
        if (t + 1 < nt) stage(cur ^ 1, (t + 1) << 6);
        __builtin_amdgcn_s_setprio(1);
#pragma unroll
        for (int kk = 0; kk < 64; kk += 32) {
            const int cb = ((kk + lk) * 2) ^ xorv;
            bf16x8 af[4], bfv[4];
#pragma unroll
            for (int m = 0; m < 4; ++m)
                af[m] = *(const bf16x8*)((char*)&As[cur][0][0] + (wr * 64 + m * 16 + lr) * 128 + cb);
#pragma unroll
            for (int n = 0; n < 4; ++n)
                bfv[n] = *(const bf16x8*)((char*)&Bs[cur][0][0] + (wc * 64 + n * 16 + lr) * 128 + cb);
#pragma unroll
            for (int m = 0; m < 4; ++m)
#pragma unroll
                for (int n = 0; n < 4; ++n)
                    acc[m][n] = __builtin_amdgcn_mfma_f32_16x16x32_bf16(af[m], bfv[n], acc[m][n], 0, 0, 0);
        }
        __builtin_amdgcn_s_setprio(0);
        __builtin_amdgcn_sched_barrier(0);
        if (t + 1 < nt)
            asm volatile("s_waitcnt vmcnt(0)" ::: "memory");
        __builtin_amdgcn_s_barrier();
        __builtin_amdgcn_sched_barrier(0);
        cur ^= 1;
    }

    const int cr = (lane >> 4) * 4;
    const int cc = lane & 15;
#pragma unroll
    for (int m = 0; m < 4; ++m) {
#pragma unroll
        for (int n = 0; n < 4; ++n) {
            int c = col0 + wc * 64 + n * 16 + cc;
            float bv = bias ? bias[c] : 0.0f;
#pragma unroll
            for (int j = 0; j < 4; ++j) {
                int r = row0 + wr * 64 + m * 16 + cr + j;
                C[(size_t)r * N + c] = acc[m][n][j] + bv;
            }
        }
    }
}

// ==== rope_vt: {q/k rope}, {V 3-slab sum + LDS transpose}, {out_w cvt} ====
__global__ __launch_bounds__(256) void rope_vt(const fp16* __restrict__ qkv0,
                                               bf16* __restrict__ qb,
                                               bf16* __restrict__ kb,
                                               bf16* __restrict__ vbT,
                                               const float* __restrict__ ow,
                                               bf16* __restrict__ owb) {
    __shared__ bf16 tile[64][65];
    const fp16* qkv1 = qkv0 + (size_t)NTOK * NQKV;
    const fp16* qkv2 = qkv1 + (size_t)NTOK * NQKV;
    int blk = blockIdx.x;
    const int tid = threadIdx.x;
    if (blk < 6144) {                        // --- q/k rope ---
        int gid = blk * 256 + tid;
        int d = gid & 31;
        int h = (gid >> 5) % NHEADS;
        int n = gid / (32 * NHEADS);
        int s = n & (SEQ - 1);
        int b = n >> 10;
        float inv = __expf(-(float)d * 0.28782313662425574f);  // 10000^(-d/32)
        float th = (float)s * inv;
        float sn, cs;
        sincosf(th, &sn, &cs);
        size_t src = (size_t)n * NQKV + h * 64 + d;
        auto rd = [&](size_t idx) {
            return __half2float(qkv0[idx]) + __half2float(qkv1[idx]) + __half2float(qkv2[idx]);
        };
        float q0 = rd(src),       q1 = rd(src + 32);
        float k0 = rd(src + 768), k1 = rd(src + 800);
        int bh = b * NHEADS + h;
        size_t dst = ((size_t)bh * SEQ + s) * 64 + d;
        const float QS = 0.18033688011f;     // 0.125 * log2(e)
        qb[dst]      = __float2bfloat16((q0 * cs - q1 * sn) * QS);
        qb[dst + 32] = __float2bfloat16((q1 * cs + q0 * sn) * QS);
        kb[dst]      = __float2bfloat16(k0 * cs - k1 * sn);
        kb[dst + 32] = __float2bfloat16(k1 * cs + k0 * sn);
        return;
    }
    blk -= 6144;
    if (blk < 768) {                         // --- V transpose ---
        int bh = blk >> 4, st = blk & 15;
        int b = bh / NHEADS, h = bh - b * NHEADS;
        {
            int s = tid >> 2, d0 = (tid & 3) * 16;
            size_t src = (size_t)(b * SEQ + st * 64 + s) * NQKV + 1536 + h * 64 + d0;
#pragma unroll
            for (int c = 0; c < 2; ++c) {
                h16x8 a0 = *(const h16x8*)(qkv0 + src + c * 8);
                h16x8 a1 = *(const h16x8*)(qkv1 + src + c * 8);
                h16x8 a2 = *(const h16x8*)(qkv2 + src + c * 8);
#pragma unroll
                for (int j = 0; j < 8; ++j)
                    tile[s][d0 + c * 8 + j] =
                        __float2bfloat16((float)a0[j] + (float)a1[j] + (float)a2[j]);
            }
        }
        __syncthreads();
        {
            int d = tid >> 2, s0 = (tid & 3) * 16;
            bf16 out[16];
#pragma unroll
            for (int i = 0; i < 16; ++i) out[i] = tile[s0 + i][d];
            bf16* dst = vbT + ((size_t)bh * 64 + d) * SEQ + st * 64 + s0;
            *(bf16x8*)(dst)     = *(bf16x8*)&out[0];
            *(bf16x8*)(dst + 8) = *(bf16x8*)&out[8];
        }
        return;
    }
    blk -= 768;                              // --- out_w cvt (post-GEMM1 alias) ---
    int gid = blk * 256 + tid;
    owb[gid] = __float2bfloat16(ow[gid]);
}

// ---- MFMA flash attention: single-buffer K/V (25.2KB LDS -> 4 blocks/CU,
//      16 waves/CU) + T14 async reg-staging (load t+1 to regs under compute) ----
__global__ __launch_bounds__(256, 4) void attn_mfma(const bf16* __restrict__ qb,
                                                    const bf16* __restrict__ kb,
                                                    const bf16* __restrict__ vbT,
                                                    bf16* __restrict__ attnb) {
    __shared__ __align__(16) bf16 Kls[64][64];    // 8KB
    __shared__ __align__(16) bf16 Vt[64][64];     // 8KB
    __shared__ __align__(16) bf16 Pls[4][16][72]; // 9.2KB

    const int tid  = threadIdx.x;
    const int lane = tid & 63;
    const int w    = tid >> 6;
    const int bh   = blockIdx.x;
    const int b    = bh / NHEADS, h = bh - b * NHEADS;
    const int qt   = blockIdx.y;

    const bf16* qhead  = qb  + (size_t)bh * SEQ * 64;
    const char* khead  = (const char*)(kb  + (size_t)bh * SEQ * 64);
    const char* vheadT = (const char*)(vbT + (size_t)bh * 64 * SEQ);

    const int lr = lane & 15;
    const int lg = lane >> 4;
    const int xorv = (lr & 7) << 4;

    // per-thread staging addresses (pre-swizzled global, linear LDS dest)
    const int r0 = tid >> 3;            // chunk 0 row
    const int r1 = (tid + 256) >> 3;    // chunk 1 row
    const int sw0 = ((tid & 7) * 16) ^ ((r0 & 7) << 4);
    const int sw1 = ((tid & 7) * 16) ^ ((r1 & 7) << 4);

    bf16x8 qf[2];
    {
        const bf16* qrow = qhead + (size_t)(qt * 64 + w * 16 + lr) * 64 + lg * 8;
        qf[0] = *(const bf16x8*)qrow;
        qf[1] = *(const bf16x8*)(qrow + 32);
    }

    f32x4 oacc[4];
#pragma unroll
    for (int n = 0; n < 4; ++n) oacc[n] = f32x4{0.f, 0.f, 0.f, 0.f};
    float mrun[4], lsum[4];
#pragma unroll
    for (int j = 0; j < 4; ++j) { mrun[j] = -3.0e38f; lsum[j] = 0.0f; }

    bf16x8 kst0, kst1, vst0, vst1;   // staging regs (16 VGPR)
    auto load_regs = [&](int t) {
        kst0 = *(const bf16x8*)(khead + (size_t)(t * 64 + r0) * 128 + sw0);
        kst1 = *(const bf16x8*)(khead + (size_t)(t * 64 + r1) * 128 + sw1);
        vst0 = *(const bf16x8*)(vheadT + (size_t)r0 * (SEQ * 2) + t * 128 + sw0);
        vst1 = *(const bf16x8*)(vheadT + (size_t)r1 * (SEQ * 2) + t * 128 + sw1);
    };
    auto write_lds = [&]() {
        *(bf16x8*)((char*)&Kls[0][0] + tid * 16)       = kst0;
        *(bf16x8*)((char*)&Kls[0][0] + (tid + 256) * 16) = kst1;
        *(bf16x8*)((char*)&Vt[0][0] + tid * 16)        = vst0;
        *(bf16x8*)((char*)&Vt[0][0] + (tid + 256) * 16) = vst1;
    };

    load_regs(0);
    asm volatile("s_waitcnt vmcnt(0)" ::: "memory");
    write_lds();
    asm volatile("s_waitcnt lgkmcnt(0)" ::: "memory");
    __builtin_amdgcn_s_barrier();

    for (int t = 0; t < SEQ / 64; ++t) {
        if (t + 1 < SEQ / 64) load_regs(t + 1);   // T14: issue early, lands under compute

        f32x4 sacc[4];   // scores in log2 domain (Q pre-scaled)
#pragma unroll
        for (int n = 0; n < 4; ++n) sacc[n] = f32x4{0.f, 0.f, 0.f, 0.f};
        __builtin_amdgcn_s_setprio(1);
#pragma unroll
        for (int c = 0; c < 2; ++c)
#pragma unroll
            for (int n = 0; n < 4; ++n) {
                bf16x8 kf = *(const bf16x8*)((char*)&Kls[0][0] +
                                             (n * 16 + lr) * 128 + (((c * 32 + lg * 8) * 2) ^ xorv));
                sacc[n] = __builtin_amdgcn_mfma_f32_16x16x32_bf16(qf[c], kf, sacc[n], 0, 0, 0);
            }
        __builtin_amdgcn_s_setprio(0);

        // T13 defer-max in log2 units (11.5 ≈ 8 nats)
        float rowmax[4];
        bool viol = false;
#pragma unroll
        for (int j = 0; j < 4; ++j) {
            rowmax[j] = fmaxf(fmaxf(sacc[0][j], sacc[1][j]), fmaxf(sacc[2][j], sacc[3][j]));
            viol |= rowmax[j] > mrun[j] + 11.5f;
        }
        if (__ballot(viol) != 0ull) {
#pragma unroll
            for (int j = 0; j < 4; ++j) {
                float mx = rowmax[j];
                mx = fmaxf(mx, __shfl_xor(mx, 1));
                mx = fmaxf(mx, __shfl_xor(mx, 2));
                mx = fmaxf(mx, __shfl_xor(mx, 4));
                mx = fmaxf(mx, __shfl_xor(mx, 8));
                float mnew = fmaxf(mrun[j], mx);
                float csc = exp2f(mrun[j] - mnew);
                mrun[j] = mnew;
                lsum[j] *= csc;
#pragma unroll
                for (int n = 0; n < 4; ++n) oacc[n][j] *= csc;
            }
        }

        float pj[4][4];
#pragma unroll
        for (int j = 0; j < 4; ++j) {
            float p0 = exp2f(sacc[0][j] - mrun[j]);
            float p1 = exp2f(sacc[1][j] - mrun[j]);
            float p2 = exp2f(sacc[2][j] - mrun[j]);
            float p3 = exp2f(sacc[3][j] - mrun[j]);
            pj[0][j] = p0; pj[1][j] = p1; pj[2][j] = p2; pj[3][j] = p3;
            lsum[j] += (p0 + p1) + (p2 + p3);
        }

#pragma unroll
        for (int n = 0; n < 4; ++n)
#pragma unroll
            for (int j = 0; j < 4; ++j)
                Pls[w][lg * 4 + j][n * 16 + lr] = __float2bfloat16(pj[n][j]);

        __builtin_amdgcn_s_setprio(1);
#pragma unroll
        for (int c = 0; c < 2; ++c) {
            bf16x8 pf = *(const bf16x8*)&Pls[w][lr][c * 32 + lg * 8];
#pragma unroll
            for (int n = 0; n < 4; ++n) {
                bf16x8 vf = *(const bf16x8*)((char*)&Vt[0][0] +
                                             (n * 16 + lr) * 128 + (((c * 32 + lg * 8) * 2) ^ xorv));
                oacc[n] = __builtin_amdgcn_mfma_f32_16x16x32_bf16(pf, vf, oacc[n], 0, 0, 0);
            }
        }
        __builtin_amdgcn_s_setprio(0);

        if (t + 1 < SEQ / 64) {
            __builtin_amdgcn_s_barrier();     // all waves done READING Kls/Vt
            asm volatile("s_waitcnt vmcnt(0)" ::: "memory");   // staged regs landed
            write_lds();
            asm volatile("s_waitcnt lgkmcnt(0)" ::: "memory");
            __builtin_amdgcn_s_barrier();     // writes visible to all waves
        }
    }

#pragma unroll
    for (int j = 0; j < 4; ++j) {
        float l = lsum[j];
        l += __shfl_xor(l, 1);
        l += __shfl_xor(l, 2);
        l += __shfl_xor(l, 4);
        l += __shfl_xor(l, 8);
        float invl = 1.0f / l;
        int tok = b * SEQ + qt * 64 + w * 16 + lg * 4 + j;
        bf16* dst = attnb + (size_t)tok * HIDDEN + h * 64;
#pragma unroll
        for (int n = 0; n < 4; ++n)
            dst[n * 16 + lr] = __float2bfloat16(oacc[n][j] * invl);
    }
}

extern "C" void kernel_launch(void* const* d_in, const int* in_sizes, int n_in,
                              void* d_out, int out_size, void* d_ws, size_t ws_size,
                              hipStream_t stream) {
    const float* x   = (const float*)d_in[0];
    const float* qbw = (const float*)d_in[1];
    const float* qsw = (const float*)d_in[2];
    const float* qsc = (const float*)d_in[3];
    const float* kbw = (const float*)d_in[4];
    const float* ksw = (const float*)d_in[5];
    const float* ksc = (const float*)d_in[6];
    const float* vbw = (const float*)d_in[7];
    const float* vsw = (const float*)d_in[8];
    const float* vsc = (const float*)d_in[9];
    const float* ow  = (const float*)d_in[10];
    const float* ob  = (const float*)d_in[11];

    char* ws = (char*)d_ws;
    size_t off = 0;
    bf16*  xaug = (bf16*)(ws + off); off += (size_t)NTOK * KAUG * 2;        // 56.6 MB
    bf16*  waug = (bf16*)(ws + off); off += (size_t)NQKV * KAUG * 2;        // 31.9 MB
    fp16*  qkvp = (fp16*)(ws + off); off += (size_t)3 * NTOK * NQKV * 2;    // 56.6 MB (3 slabs)
    if (off > ws_size) return;

    bf16* attnb = xaug;                                    // xaug dead after GEMM1
    bf16* owb   = (bf16*)((char*)xaug + (8u << 20));       // ditto (written in rope_vt)
    const size_t headsz = (size_t)NTOK * 64 * NHEADS;
    bf16* qb  = waug;                                      // waug dead after GEMM1
    bf16* kb  = waug + headsz;
    bf16* vbT = waug + 2 * headsz;

    hipFuncSetAttribute(reinterpret_cast<const void*>(gemm256_8ph<3>),
                        hipFuncAttributeMaxDynamicSharedMemorySize, 131072);

    prep<<<12288 + 3 * 2304, 256, 0, stream>>>(
        x, qbw, qsw, qsc, kbw, ksw, ksc, vbw, vsw, vsc, xaug, waug);

    gemm256_8ph<3><<<dim3(NTOK / 256, NQKV / 256, 3), 512, 131072, stream>>>(
        xaug, waug, qkvp, NTOK, NQKV, KAUG);

    rope_vt<<<6144 + 768 + 2304, 256, 0, stream>>>(qkvp, qb, kb, vbT, ow, owb);
    attn_mfma<<<dim3(NBATCH * NHEADS, SEQ / 64), 256, 0, stream>>>(qb, kb, vbT, attnb);
    gemm_bt<<<dim3(NTOK / 128, HIDDEN / 128), 256, 0, stream>>>(attnb, owb, (float*)d_out, ob, NTOK, HIDDEN, HIDDEN);
}

// Round 15
// 270.653 us; speedup vs baseline: 1.0229x; 1.0026x over previous
//
#include <hip/hip_runtime.h>
#include <hip/hip_bf16.h>
#include <hip/hip_fp16.h>

#define HIDDEN 768
#define NTOK   4096
#define SEQ    1024
#define NBATCH 4
#define NHEADS 12
#define KAUG   (HIDDEN * 9)   // 6912
#define NQKV   (3 * HIDDEN)   // 2304

using bf16 = __hip_bfloat16;
using fp16 = __half;
typedef __attribute__((ext_vector_type(4))) float f32x4;
typedef __attribute__((ext_vector_type(8))) short bf16x8;
typedef __attribute__((ext_vector_type(8))) _Float16 h16x8;

__device__ inline void gload_lds16(const void* g, void* l) {
    __builtin_amdgcn_global_load_lds((const __attribute__((address_space(1))) void*)g,
                                     (__attribute__((address_space(3))) void*)l, 16, 0, 0);
}

// ==== prep: X_aug + W_aug in ONE launch ====
__global__ __launch_bounds__(256) void prep(const float* __restrict__ x,
        const float* __restrict__ qbw, const float* __restrict__ qsw, const float* __restrict__ qsc,
        const float* __restrict__ kbw, const float* __restrict__ ksw, const float* __restrict__ ksc,
        const float* __restrict__ vbw, const float* __restrict__ vsw, const float* __restrict__ vsc,
        bf16* __restrict__ xa, bf16* __restrict__ wa) {
    int blk = blockIdx.x;
    const int tid = threadIdx.x;
    if (blk < 12288) {                       // --- X_aug ---
        int gid = blk * 256 + tid;
        float xv = x[gid];
        int n = gid / HIDDEN;
        int i = gid - n * HIDDEN;
        float sil = xv / (1.0f + __expf(-xv));
        float g[12];
#pragma unroll
        for (int k = 0; k < 12; ++k) g[k] = (float)(k - 3) * 0.4f - 1.0f;
        float b[11];
#pragma unroll
        for (int c = 0; c < 11; ++c) b[c] = (xv >= g[c] && xv < g[c + 1]) ? 1.0f : 0.0f;
#pragma unroll
        for (int k = 1; k <= 3; ++k) {
#pragma unroll
            for (int c = 0; c < 11; ++c) {
                if (c < 11 - k) {
                    float left  = (xv - g[c]) / (g[c + k] - g[c]) * b[c];
                    float right = (g[c + k + 1] - xv) / (g[c + k + 1] - g[c + 1]) * b[c + 1];
                    b[c] = left + right;
                }
            }
        }
        bf16* dst = xa + (size_t)n * KAUG + (size_t)i * 9;
        dst[0] = __float2bfloat16(sil);
#pragma unroll
        for (int c = 0; c < 8; ++c) dst[1 + c] = __float2bfloat16(b[c]);
        return;
    }
    blk -= 12288;                            // --- W_aug q/k/v ---
    int job = blk / 2304;
    int gid = (blk - job * 2304) * 256 + tid;
    const float* bw = job == 0 ? qbw : (job == 1 ? kbw : vbw);
    const float* sw = job == 0 ? qsw : (job == 1 ? ksw : vsw);
    const float* sc = job == 0 ? qsc : (job == 1 ? ksc : vsc);
    float bwv = bw[gid];
    float scv = sc[gid];
    bf16* dst = wa + (size_t)job * HIDDEN * KAUG + (size_t)gid * 9;
    dst[0] = __float2bfloat16(bwv);
#pragma unroll
    for (int c = 0; c < 8; ++c)
        dst[1 + c] = __float2bfloat16(sw[(size_t)gid * 8 + c] * scv);
}

// ==== 8-phase 256x256 GEMM: C_slab[z] = A@B^T (K-slice z), fp16 plain stores ====
template <int KSPLIT>
__global__ __launch_bounds__(512, 2) void gemm256_8ph(const bf16* __restrict__ A,
                                                      const bf16* __restrict__ B,
                                                      fp16* __restrict__ C,
                                                      int M, int N, int K) {
    extern __shared__ char smem[];   // 128 KiB: [buf(2)][half(4)] x 16KB
    const int tid  = threadIdx.x;
    const int lane = tid & 63;
    const int wave = tid >> 6;
    const int wm = wave >> 2;
    const int wn = wave & 3;

    // XCD-OWNERSHIP swizzle (replaces generic T1): grid 16x9=144 = 8 XCDs x 18
    // jobs. block->XCD = lin%8 (144%8==0 so z doesn't shift it). XCD x owns
    // A-row-panels {2x,2x+1} (2.36MB -> L2-resident across all 9 col jobs)
    // x all 9 B-col panels (streamed; B-slice 10.6MB stays L3-hot).
    int lin = blockIdx.y * gridDim.x + blockIdx.x;
    int row0, col0;
    if (gridDim.x == 16 && gridDim.y == 9) {
        int xcd = lin & 7;
        int idx = lin >> 3;              // 0..17
        int rsel = (idx >= 9) ? 1 : 0;
        row0 = (xcd * 2 + rsel) * 256;
        col0 = (idx - rsel * 9) * 256;
    } else {                             // fallback: bijective T1
        const int nwg = gridDim.x * gridDim.y;
        const int per = nwg >> 3;
        int swz = (lin & 7) * per + (lin >> 3);
        row0 = (swz % gridDim.x) * 256;
        col0 = (swz / gridDim.x) * 256;
    }

    const int kslice = K / KSPLIT;
    const int koff = blockIdx.z * kslice;
    const int ntiles = kslice >> 6;
    fp16* Cs = C + (size_t)blockIdx.z * M * N;

    const int lr = lane & 15;
    const int lk = (lane >> 4) * 8;
    const int xorv = (lr & 7) << 4;

    f32x4 acc[8][4];
#pragma unroll
    for (int m = 0; m < 8; ++m)
#pragma unroll
        for (int n = 0; n < 4; ++n) acc[m][n] = f32x4{0.f, 0.f, 0.f, 0.f};

    auto stage_half = [&](int buf, int half, int t) {
#pragma unroll
        for (int j = 0; j < 2; ++j) {
            int idx = tid + j * 512;
            int r = idx >> 3;
            int swzc = ((((idx & 7) * 16) ^ ((r & 7) << 4)) >> 1);
            const bf16* src = (half < 2)
                ? A + (size_t)(row0 + half * 128 + r) * K + koff + t * 64 + swzc
                : B + (size_t)(col0 + (half - 2) * 128 + r) * K + koff + t * 64 + swzc;
            gload_lds16(src, smem + ((size_t)(buf * 4 + half) << 14) + idx * 16);
        }
    };
    auto rdA = [&](int buf, int mh, bf16x8 (&af)[4][2]) {
        const char* Ab = smem + ((size_t)(buf * 4 + wm) << 14);
#pragma unroll
        for (int m = 0; m < 4; ++m)
#pragma unroll
            for (int kk = 0; kk < 2; ++kk)
                af[m][kk] = *(const bf16x8*)(Ab + (mh * 64 + m * 16 + lr) * 128 +
                                             (((kk * 32 + lk) * 2) ^ xorv));
    };
    auto rdB = [&](int buf, int nh, bf16x8 (&bf)[2][2]) {
        const char* Bb = smem + ((size_t)(buf * 4 + 2 + (wn >> 1)) << 14);
#pragma unroll
        for (int n = 0; n < 2; ++n)
#pragma unroll
            for (int kk = 0; kk < 2; ++kk)
                bf[n][kk] = *(const bf16x8*)(Bb + ((wn & 1) * 64 + nh * 32 + n * 16 + lr) * 128 +
                                             (((kk * 32 + lk) * 2) ^ xorv));
    };

    stage_half(0, 0, 0); stage_half(0, 1, 0); stage_half(0, 2, 0); stage_half(0, 3, 0);
    stage_half(1, 2, 1); stage_half(1, 3, 1);
    asm volatile("s_waitcnt vmcnt(0)" ::: "memory");
    __builtin_amdgcn_s_barrier();

    bf16x8 af[4][2], bf0[2][2], bf1[2][2];

#define QUAD(MH, NH, BF)                                                         \
    __builtin_amdgcn_s_setprio(1);                                               \
    _Pragma("unroll") for (int m = 0; m < 4; ++m)                                \
        _Pragma("unroll") for (int n = 0; n < 2; ++n)                            \
            _Pragma("unroll") for (int kk = 0; kk < 2; ++kk)                     \
                acc[(MH)*4 + m][(NH)*2 + n] = __builtin_amdgcn_mfma_f32_16x16x32_bf16( \
                    af[m][kk], BF[n][kk], acc[(MH)*4 + m][(NH)*2 + n], 0, 0, 0); \
    __builtin_amdgcn_s_setprio(0);

    for (int u = 0; u < ntiles; ++u) {
        const int buf = u & 1, nbuf = buf ^ 1;
        rdA(buf, 0, af);
        rdB(buf, 0, bf0);
        if (u + 1 < ntiles) stage_half(nbuf, 0, u + 1);
        __builtin_amdgcn_s_barrier();
        asm volatile("s_waitcnt lgkmcnt(0)" ::: "memory");
        __builtin_amdgcn_sched_barrier(0);
        QUAD(0, 0, bf0)
        __builtin_amdgcn_sched_barrier(0);
        __builtin_amdgcn_s_barrier();
        rdB(buf, 1, bf1);
        if (u + 1 < ntiles) stage_half(nbuf, 1, u + 1);
        __builtin_amdgcn_s_barrier();
        asm volatile("s_waitcnt lgkmcnt(0)" ::: "memory");
        __builtin_amdgcn_sched_barrier(0);
        QUAD(0, 1, bf1)
        __builtin_amdgcn_sched_barrier(0);
        __builtin_amdgcn_s_barrier();
        rdA(buf, 1, af);
        if (u + 2 < ntiles) stage_half(buf, 2, u + 2);
        __builtin_amdgcn_s_barrier();
        asm volatile("s_waitcnt lgkmcnt(0)" ::: "memory");
        __builtin_amdgcn_sched_barrier(0);
        QUAD(1, 1, bf1)
        __builtin_amdgcn_sched_barrier(0);
        __builtin_amdgcn_s_barrier();
        if (u + 2 < ntiles) {
            stage_half(buf, 3, u + 2);
            asm volatile("s_waitcnt vmcnt(4)" ::: "memory");
        } else {
            asm volatile("s_waitcnt vmcnt(0)" ::: "memory");
        }
        __builtin_amdgcn_s_barrier();
        __builtin_amdgcn_sched_barrier(0);
        QUAD(1, 0, bf0)
        __builtin_amdgcn_sched_barrier(0);
        __builtin_amdgcn_s_barrier();
    }
#undef QUAD

    const int cr = (lane >> 4) * 4;
    const int cc = lane & 15;
#pragma unroll
    for (int am = 0; am < 8; ++am) {
#pragma unroll
        for (int an = 0; an < 4; ++an) {
            int c = col0 + wn * 64 + an * 16 + cc;
#pragma unroll
            for (int j = 0; j < 4; ++j) {
                int r = row0 + wm * 128 + am * 16 + cr + j;
                Cs[(size_t)r * N + c] = __float2half(acc[am][an][j]);
            }
        }
    }
}

// ---- 128x128 GEMM (out-proj): swizzled LDS, 2-phase dbuf, T1 XCD swizzle ----
__global__ __launch_bounds__(256) void gemm_bt(const bf16* __restrict__ A,
                                               const bf16* __restrict__ B,
                                               float* __restrict__ C,
                                               const float* __restrict__ bias,
                                               int M, int N, int K) {
    __shared__ __align__(16) bf16 As[2][128][64];
    __shared__ __align__(16) bf16 Bs[2][128][64];
    const int tid  = threadIdx.x;
    const int lane = tid & 63;
    const int wave = tid >> 6;
    const int wr = wave >> 1, wc = wave & 1;

    // T1 bijective XCD swizzle (nwg = 32*6 = 192, 192%8==0)
    const int gx = gridDim.x;
    const int per = (gx * gridDim.y) >> 3;
    int lin = blockIdx.y * gx + blockIdx.x;
    int swz = (lin & 7) * per + (lin >> 3);
    const int row0 = (swz % gx) * 128;
    const int col0 = (swz / gx) * 128;

    f32x4 acc[4][4];
#pragma unroll
    for (int m = 0; m < 4; ++m)
#pragma unroll
        for (int n = 0; n < 4; ++n) acc[m][n] = f32x4{0.f, 0.f, 0.f, 0.f};

    const int srow = tid >> 3;
    const int scol = ((((tid & 7) * 16) ^ ((srow & 7) << 4)) >> 1);
    const bf16* aptr = A + (size_t)(row0 + srow) * K + scol;
    const bf16* bptr = B + (size_t)(col0 + srow) * K + scol;

    const int lr = lane & 15;
    const int lk = (lane >> 4) * 8;
    const int xorv = (lr & 7) << 4;
    const int nt = K >> 6;

    auto stage = [&](int buf, int k0) {
        char* adst = (char*)&As[buf][0][0] + tid * 16;
        char* bdst = (char*)&Bs[buf][0][0] + tid * 16;
#pragma unroll
        for (int j = 0; j < 4; ++j)
            gload_lds16(aptr + (size_t)j * 32 * K + k0, adst + j * 4096);
#pragma unroll
        for (int j = 0; j < 4; ++j)
            gload_lds16(bptr + (size_t)j * 32 * K + k0, bdst + j * 4096);
    };

    stage(0, 0);
    asm volatile("s_waitcnt vmcnt(0)" ::: "memory");
    __syncthreads();

    int cur = 0;
    for (int t = 0; t < nt; ++t) {
        if (t + 1 < nt) stage(cur ^ 1, (t + 1) << 6);
        __builtin_amdgcn_s_setprio(1);
#pragma unroll
        for (int kk = 0; kk < 64; kk += 32) {
            const int cb = ((kk + lk) * 2) ^ xorv;
            bf16x8 af[4], bfv[4];
#pragma unroll
            for (int m = 0; m < 4; ++m)
                af[m] = *(const bf16x8*)((char*)&As[cur][0][0] + (wr * 64 + m * 16 + lr) * 128 + cb);
#pragma unroll
            for (int n = 0; n < 4; ++n)
                bfv[n] = *(const bf16x8*)((char*)&Bs[cur][0][0] + (wc * 64 + n * 16 + lr) * 128 + cb);
#pragma unroll
            for (int m = 0; m < 4; ++m)
#pragma unroll
                for (int n = 0; n < 4; ++n)
                    acc[m][n] = __builtin_amdgcn_mfma_f32_16x16x32_bf16(af[m], bfv[n], acc[m][n], 0, 0, 0);
        }
        __builtin_amdgcn_s_setprio(0);
        __builtin_amdgcn_sched_barrier(0);
        if (t + 1 < nt)
            asm volatile("s_waitcnt vmcnt(0)" ::: "memory");
        __builtin_amdgcn_s_barrier();
        __builtin_amdgcn_sched_barrier(0);
        cur ^= 1;
    }

    const int cr = (lane >> 4) * 4;
    const int cc = lane & 15;
#pragma unroll
    for (int m = 0; m < 4; ++m) {
#pragma unroll
        for (int n = 0; n < 4; ++n) {
            int c = col0 + wc * 64 + n * 16 + cc;
            float bv = bias ? bias[c] : 0.0f;
#pragma unroll
            for (int j = 0; j < 4; ++j) {
                int r = row0 + wr * 64 + m * 16 + cr + j;
                C[(size_t)r * N + c] = acc[m][n][j] + bv;
            }
        }
    }
}

// ==== rope_vt: {q/k rope}, {V 3-slab sum + LDS transpose}, {out_w cvt} ====
__global__ __launch_bounds__(256) void rope_vt(const fp16* __restrict__ qkv0,
                                               bf16* __restrict__ qb,
                                               bf16* __restrict__ kb,
                                               bf16* __restrict__ vbT,
                                               const float* __restrict__ ow,
                                               bf16* __restrict__ owb) {
    __shared__ bf16 tile[64][65];
    const fp16* qkv1 = qkv0 + (size_t)NTOK * NQKV;
    const fp16* qkv2 = qkv1 + (size_t)NTOK * NQKV;
    int blk = blockIdx.x;
    const int tid = threadIdx.x;
    if (blk < 6144) {                        // --- q/k rope ---
        int gid = blk * 256 + tid;
        int d = gid & 31;
        int h = (gid >> 5) % NHEADS;
        int n = gid / (32 * NHEADS);
        int s = n & (SEQ - 1);
        int b = n >> 10;
        float inv = __expf(-(float)d * 0.28782313662425574f);  // 10000^(-d/32)
        float th = (float)s * inv;
        float sn, cs;
        sincosf(th, &sn, &cs);
        size_t src = (size_t)n * NQKV + h * 64 + d;
        auto rd = [&](size_t idx) {
            return __half2float(qkv0[idx]) + __half2float(qkv1[idx]) + __half2float(qkv2[idx]);
        };
        float q0 = rd(src),       q1 = rd(src + 32);
        float k0 = rd(src + 768), k1 = rd(src + 800);
        int bh = b * NHEADS + h;
        size_t dst = ((size_t)bh * SEQ + s) * 64 + d;
        const float QS = 0.18033688011f;     // 0.125 * log2(e)
        qb[dst]      = __float2bfloat16((q0 * cs - q1 * sn) * QS);
        qb[dst + 32] = __float2bfloat16((q1 * cs + q0 * sn) * QS);
        kb[dst]      = __float2bfloat16(k0 * cs - k1 * sn);
        kb[dst + 32] = __float2bfloat16(k1 * cs + k0 * sn);
        return;
    }
    blk -= 6144;
    if (blk < 768) {                         // --- V transpose ---
        int bh = blk >> 4, st = blk & 15;
        int b = bh / NHEADS, h = bh - b * NHEADS;
        {
            int s = tid >> 2, d0 = (tid & 3) * 16;
            size_t src = (size_t)(b * SEQ + st * 64 + s) * NQKV + 1536 + h * 64 + d0;
#pragma unroll
            for (int c = 0; c < 2; ++c) {
                h16x8 a0 = *(const h16x8*)(qkv0 + src + c * 8);
                h16x8 a1 = *(const h16x8*)(qkv1 + src + c * 8);
                h16x8 a2 = *(const h16x8*)(qkv2 + src + c * 8);
#pragma unroll
                for (int j = 0; j < 8; ++j)
                    tile[s][d0 + c * 8 + j] =
                        __float2bfloat16((float)a0[j] + (float)a1[j] + (float)a2[j]);
            }
        }
        __syncthreads();
        {
            int d = tid >> 2, s0 = (tid & 3) * 16;
            bf16 out[16];
#pragma unroll
            for (int i = 0; i < 16; ++i) out[i] = tile[s0 + i][d];
            bf16* dst = vbT + ((size_t)bh * 64 + d) * SEQ + st * 64 + s0;
            *(bf16x8*)(dst)     = *(bf16x8*)&out[0];
            *(bf16x8*)(dst + 8) = *(bf16x8*)&out[8];
        }
        return;
    }
    blk -= 768;                              // --- out_w cvt (post-GEMM1 alias) ---
    int gid = blk * 256 + tid;
    owb[gid] = __float2bfloat16(ow[gid]);
}

// ---- MFMA flash attention: single-buffer K/V (25.2KB LDS -> 4 blocks/CU,
//      16 waves/CU) + T14 async reg-staging (load t+1 to regs under compute) ----
__global__ __launch_bounds__(256, 4) void attn_mfma(const bf16* __restrict__ qb,
                                                    const bf16* __restrict__ kb,
                                                    const bf16* __restrict__ vbT,
                                                    bf16* __restrict__ attnb) {
    __shared__ __align__(16) bf16 Kls[64][64];    // 8KB
    __shared__ __align__(16) bf16 Vt[64][64];     // 8KB
    __shared__ __align__(16) bf16 Pls[4][16][72]; // 9.2KB

    const int tid  = threadIdx.x;
    const int lane = tid & 63;
    const int w    = tid >> 6;
    const int bh   = blockIdx.x;
    const int b    = bh / NHEADS, h = bh - b * NHEADS;
    const int qt   = blockIdx.y;

    const bf16* qhead  = qb  + (size_t)bh * SEQ * 64;
    const char* khead  = (const char*)(kb  + (size_t)bh * SEQ * 64);
    const char* vheadT = (const char*)(vbT + (size_t)bh * 64 * SEQ);

    const int lr = lane & 15;
    const int lg = lane >> 4;
    const int xorv = (lr & 7) << 4;

    const int r0 = tid >> 3;
    const int r1 = (tid + 256) >> 3;
    const int sw0 = ((tid & 7) * 16) ^ ((r0 & 7) << 4);
    const int sw1 = ((tid & 7) * 16) ^ ((r1 & 7) << 4);

    bf16x8 qf[2];
    {
        const bf16* qrow = qhead + (size_t)(qt * 64 + w * 16 + lr) * 64 + lg * 8;
        qf[0] = *(const bf16x8*)qrow;
        qf[1] = *(const bf16x8*)(qrow + 32);
    }

    f32x4 oacc[4];
#pragma unroll
    for (int n = 0; n < 4; ++n) oacc[n] = f32x4{0.f, 0.f, 0.f, 0.f};
    float mrun[4], lsum[4];
#pragma unroll
    for (int j = 0; j < 4; ++j) { mrun[j] = -3.0e38f; lsum[j] = 0.0f; }

    bf16x8 kst0, kst1, vst0, vst1;
    auto load_regs = [&](int t) {
        kst0 = *(const bf16x8*)(khead + (size_t)(t * 64 + r0) * 128 + sw0);
        kst1 = *(const bf16x8*)(khead + (size_t)(t * 64 + r1) * 128 + sw1);
        vst0 = *(const bf16x8*)(vheadT + (size_t)r0 * (SEQ * 2) + t * 128 + sw0);
        vst1 = *(const bf16x8*)(vheadT + (size_t)r1 * (SEQ * 2) + t * 128 + sw1);
    };
    auto write_lds = [&]() {
        *(bf16x8*)((char*)&Kls[0][0] + tid * 16)         = kst0;
        *(bf16x8*)((char*)&Kls[0][0] + (tid + 256) * 16) = kst1;
        *(bf16x8*)((char*)&Vt[0][0] + tid * 16)          = vst0;
        *(bf16x8*)((char*)&Vt[0][0] + (tid + 256) * 16)  = vst1;
    };

    load_regs(0);
    asm volatile("s_waitcnt vmcnt(0)" ::: "memory");
    write_lds();
    asm volatile("s_waitcnt lgkmcnt(0)" ::: "memory");
    __builtin_amdgcn_s_barrier();

    for (int t = 0; t < SEQ / 64; ++t) {
        if (t + 1 < SEQ / 64) load_regs(t + 1);

        f32x4 sacc[4];
#pragma unroll
        for (int n = 0; n < 4; ++n) sacc[n] = f32x4{0.f, 0.f, 0.f, 0.f};
        __builtin_amdgcn_s_setprio(1);
#pragma unroll
        for (int c = 0; c < 2; ++c)
#pragma unroll
            for (int n = 0; n < 4; ++n) {
                bf16x8 kf = *(const bf16x8*)((char*)&Kls[0][0] +
                                             (n * 16 + lr) * 128 + (((c * 32 + lg * 8) * 2) ^ xorv));
                sacc[n] = __builtin_amdgcn_mfma_f32_16x16x32_bf16(qf[c], kf, sacc[n], 0, 0, 0);
            }
        __builtin_amdgcn_s_setprio(0);

        float rowmax[4];
        bool viol = false;
#pragma unroll
        for (int j = 0; j < 4; ++j) {
            rowmax[j] = fmaxf(fmaxf(sacc[0][j], sacc[1][j]), fmaxf(sacc[2][j], sacc[3][j]));
            viol |= rowmax[j] > mrun[j] + 11.5f;
        }
        if (__ballot(viol) != 0ull) {
#pragma unroll
            for (int j = 0; j < 4; ++j) {
                float mx = rowmax[j];
                mx = fmaxf(mx, __shfl_xor(mx, 1));
                mx = fmaxf(mx, __shfl_xor(mx, 2));
                mx = fmaxf(mx, __shfl_xor(mx, 4));
                mx = fmaxf(mx, __shfl_xor(mx, 8));
                float mnew = fmaxf(mrun[j], mx);
                float csc = exp2f(mrun[j] - mnew);
                mrun[j] = mnew;
                lsum[j] *= csc;
#pragma unroll
                for (int n = 0; n < 4; ++n) oacc[n][j] *= csc;
            }
        }

        float pj[4][4];
#pragma unroll
        for (int j = 0; j < 4; ++j) {
            float p0 = exp2f(sacc[0][j] - mrun[j]);
            float p1 = exp2f(sacc[1][j] - mrun[j]);
            float p2 = exp2f(sacc[2][j] - mrun[j]);
            float p3 = exp2f(sacc[3][j] - mrun[j]);
            pj[0][j] = p0; pj[1][j] = p1; pj[2][j] = p2; pj[3][j] = p3;
            lsum[j] += (p0 + p1) + (p2 + p3);
        }

#pragma unroll
        for (int n = 0; n < 4; ++n)
#pragma unroll
            for (int j = 0; j < 4; ++j)
                Pls[w][lg * 4 + j][n * 16 + lr] = __float2bfloat16(pj[n][j]);

        __builtin_amdgcn_s_setprio(1);
#pragma unroll
        for (int c = 0; c < 2; ++c) {
            bf16x8 pf = *(const bf16x8*)&Pls[w][lr][c * 32 + lg * 8];
#pragma unroll
            for (int n = 0; n < 4; ++n) {
                bf16x8 vf = *(const bf16x8*)((char*)&Vt[0][0] +
                                             (n * 16 + lr) * 128 + (((c * 32 + lg * 8) * 2) ^ xorv));
                oacc[n] = __builtin_amdgcn_mfma_f32_16x16x32_bf16(pf, vf, oacc[n], 0, 0, 0);
            }
        }
        __builtin_amdgcn_s_setprio(0);

        if (t + 1 < SEQ / 64) {
            __builtin_amdgcn_s_barrier();
            asm volatile("s_waitcnt vmcnt(0)" ::: "memory");
            write_lds();
            asm volatile("s_waitcnt lgkmcnt(0)" ::: "memory");
            __builtin_amdgcn_s_barrier();
        }
    }

#pragma unroll
    for (int j = 0; j < 4; ++j) {
        float l = lsum[j];
        l += __shfl_xor(l, 1);
        l += __shfl_xor(l, 2);
        l += __shfl_xor(l, 4);
        l += __shfl_xor(l, 8);
        float invl = 1.0f / l;
        int tok = b * SEQ + qt * 64 + w * 16 + lg * 4 + j;
        bf16* dst = attnb + (size_t)tok * HIDDEN + h * 64;
#pragma unroll
        for (int n = 0; n < 4; ++n)
            dst[n * 16 + lr] = __float2bfloat16(oacc[n][j] * invl);
    }
}

extern "C" void kernel_launch(void* const* d_in, const int* in_sizes, int n_in,
                              void* d_out, int out_size, void* d_ws, size_t ws_size,
                              hipStream_t stream) {
    const float* x   = (const float*)d_in[0];
    const float* qbw = (const float*)d_in[1];
    const float* qsw = (const float*)d_in[2];
    const float* qsc = (const float*)d_in[3];
    const float* kbw = (const float*)d_in[4];
    const float* ksw = (const float*)d_in[5];
    const float* ksc = (const float*)d_in[6];
    const float* vbw = (const float*)d_in[7];
    const float* vsw = (const float*)d_in[8];
    const float* vsc = (const float*)d_in[9];
    const float* ow  = (const float*)d_in[10];
    const float* ob  = (const float*)d_in[11];

    char* ws = (char*)d_ws;
    size_t off = 0;
    bf16*  xaug = (bf16*)(ws + off); off += (size_t)NTOK * KAUG * 2;        // 56.6 MB
    bf16*  waug = (bf16*)(ws + off); off += (size_t)NQKV * KAUG * 2;        // 31.9 MB
    fp16*  qkvp = (fp16*)(ws + off); off += (size_t)3 * NTOK * NQKV * 2;    // 56.6 MB (3 slabs)
    if (off > ws_size) return;

    bf16* attnb = xaug;                                    // xaug dead after GEMM1
    bf16* owb   = (bf16*)((char*)xaug + (8u << 20));       // ditto (written in rope_vt)
    const size_t headsz = (size_t)NTOK * 64 * NHEADS;
    bf16* qb  = waug;                                      // waug dead after GEMM1
    bf16* kb  = waug + headsz;
    bf16* vbT = waug + 2 * headsz;

    hipFuncSetAttribute(reinterpret_cast<const void*>(gemm256_8ph<3>),
                        hipFuncAttributeMaxDynamicSharedMemorySize, 131072);

    prep<<<12288 + 3 * 2304, 256, 0, stream>>>(
        x, qbw, qsw, qsc, kbw, ksw, ksc, vbw, vsw, vsc, xaug, waug);

    gemm256_8ph<3><<<dim3(NTOK / 256, NQKV / 256, 3), 512, 131072, stream>>>(
        xaug, waug, qkvp, NTOK, NQKV, KAUG);

    rope_vt<<<6144 + 768 + 2304, 256, 0, stream>>>(qkvp, qb, kb, vbT, ow, owb);
    attn_mfma<<<dim3(NBATCH * NHEADS, SEQ / 64), 256, 0, stream>>>(qb, kb, vbT, attnb);
    gemm_bt<<<dim3(NTOK / 128, HIDDEN / 128), 256, 0, stream>>>(attnb, owb, (float*)d_out, ob, NTOK, HIDDEN, HIDDEN);
}